// Round 1
// baseline (97.361 us; speedup 1.0000x reference)
//
#include <hip/hip_runtime.h>
#include <math.h>

#define NB 256      // batch
#define NP 784      // pixels
#define NT 200      // time samples

static constexpr float TWO_PI = 6.28318530717958647692f;

// ---------------------------------------------------------------------------
// K2: partial complex GEMM  u[b,t] = sum_p x[b,p]*v[p]*(sr+i*si)[p,t]
// Block g < GB: row-group rg = g/PC (R rows), p-chunk c = g%PC (NP/PC pixels).
// Writes partial sums up[c][b][t] (float2). Extra block g == GB computes
// Wenv[t] = DFT(waveform)[t] * env[t] into ws (needed only by K3).
// ---------------------------------------------------------------------------
template <int R, int PC>
__global__ __launch_bounds__(256) void gemm_kernel(
        const float* __restrict__ x,  const float* __restrict__ v,
        const float* __restrict__ sr, const float* __restrict__ si,
        const float* __restrict__ wr, const float* __restrict__ wi,
        const float* __restrict__ er, const float* __restrict__ ei,
        float2* __restrict__ wenv, float2* __restrict__ up)
{
    constexpr int CH = NP / PC;          // pixels per block
    constexpr int GB = (NB / R) * PC;    // gemm blocks
    __shared__ __align__(16) float xvT[CH][R];
    __shared__ float2 ctbl[NT];

    const int tid = threadIdx.x;
    const int g   = blockIdx.x;

    if (g == GB) {
        // ---- Wenv block: 200-point DFT of waveform, times envelope ----
        if (tid < NT) {
            float s, c;
            sincosf(TWO_PI * (float)tid / (float)NT, &s, &c);
            ctbl[tid] = make_float2(c, s);
        }
        __syncthreads();
        if (tid < NT) {
            const int k = tid;
            float Ar = 0.f, Ai = 0.f;
            int m = 0;                     // m = (k*n) mod NT, exact
            for (int n = 0; n < NT; ++n) {
                float2 cs = ctbl[m];       // e^{-i th} = c - i s
                float wrv = wr[n], wiv = wi[n];
                Ar += wrv * cs.x + wiv * cs.y;
                Ai += wiv * cs.x - wrv * cs.y;
                m += k; if (m >= NT) m -= NT;
            }
            float erv = er[k], eiv = ei[k];
            wenv[k] = make_float2(Ar * erv - Ai * eiv, Ar * eiv + Ai * erv);
        }
        return;
    }

    const int rg = g / PC, c = g % PC;
    const int r0 = rg * R;
    const int p0 = c * CH;

    // stage xv[r][p] = x[r0+r][p0+p] * v[p0+p], transposed for float4 broadcast
    for (int p = tid; p < CH; p += 256) {
        float vv = v[p0 + p];
        #pragma unroll
        for (int r = 0; r < R; ++r)
            xvT[p][r] = x[(size_t)(r0 + r) * NP + p0 + p] * vv;
    }
    __syncthreads();

    const int t = tid;
    if (t < NT) {
        float ar[R], ai[R];
        #pragma unroll
        for (int r = 0; r < R; ++r) { ar[r] = 0.f; ai[r] = 0.f; }
        const float* srp = sr + (size_t)p0 * NT + t;   // coalesced over lanes
        const float* sip = si + (size_t)p0 * NT + t;
        for (int j = 0; j < CH; ++j) {
            float srv = srp[(size_t)j * NT];
            float siv = sip[(size_t)j * NT];
            #pragma unroll
            for (int rr = 0; rr < R; rr += 4) {
                float4 xv = *(const float4*)&xvT[j][rr];   // LDS broadcast
                ar[rr+0] += xv.x * srv;  ai[rr+0] += xv.x * siv;
                ar[rr+1] += xv.y * srv;  ai[rr+1] += xv.y * siv;
                ar[rr+2] += xv.z * srv;  ai[rr+2] += xv.z * siv;
                ar[rr+3] += xv.w * srv;  ai[rr+3] += xv.w * siv;
            }
        }
        #pragma unroll
        for (int r = 0; r < R; ++r)
            up[((size_t)c * NB + r0 + r) * NT + t] = make_float2(ar[r], ai[r]);
    }
}

// ---------------------------------------------------------------------------
// K3: per batch-row: sum partials -> *Wenv -> Re(IFFT) via mod-table DFT ->
//     chunk max(sqrt(x^2+eps)) -> 10x10 linear -> out[b][j]
// ---------------------------------------------------------------------------
__global__ __launch_bounds__(256) void epilogue_kernel(
        const float2* __restrict__ up, int pc,
        const float2* __restrict__ wenv,
        const float* __restrict__ lw, const float* __restrict__ lb,
        float* __restrict__ out)
{
    __shared__ float2 ctbl[NT];
    __shared__ float2 s2[NT];
    __shared__ float  rbuf[NT];
    __shared__ float  cm[10];

    const int b   = blockIdx.x;
    const int tid = threadIdx.x;

    if (tid < NT) {
        float s, c;
        sincosf(TWO_PI * (float)tid / (float)NT, &s, &c);
        ctbl[tid] = make_float2(c, s);
        float ur = 0.f, ui = 0.f;
        for (int cc = 0; cc < pc; ++cc) {
            float2 pv = up[((size_t)cc * NB + b) * NT + tid];
            ur += pv.x; ui += pv.y;
        }
        float2 W = wenv[tid];
        s2[tid] = make_float2(ur * W.x - ui * W.y, ur * W.y + ui * W.x);
    }
    __syncthreads();

    if (tid < NT) {
        const int n = tid;
        float acc = 0.f;
        int m = 0;                           // m = (n*t) mod NT
        for (int t2 = 0; t2 < NT; ++t2) {
            float2 cs = ctbl[m];             // e^{+i th}
            float2 sv = s2[t2];              // broadcast
            acc += sv.x * cs.x - sv.y * cs.y;
            m += n; if (m >= NT) m -= NT;
        }
        rbuf[tid] = acc * (1.0f / (float)NT);
    }
    __syncthreads();

    if (tid < 10) {
        float mx = 0.f;
        #pragma unroll
        for (int q = 0; q < 20; ++q) {
            float xv = rbuf[tid * 20 + q];
            mx = fmaxf(mx, sqrtf(xv * xv + 1e-20f));
        }
        cm[tid] = mx;
    }
    __syncthreads();

    if (tid < 10) {
        float o = lb[tid];
        #pragma unroll
        for (int k = 0; k < 10; ++k)
            o += cm[k] * lw[tid * 10 + k];
        out[b * 10 + tid] = o;
    }
}

// ---------------------------------------------------------------------------
extern "C" void kernel_launch(void* const* d_in, const int* in_sizes, int n_in,
                              void* d_out, int out_size, void* d_ws, size_t ws_size,
                              hipStream_t stream)
{
    const float* x  = (const float*)d_in[0];
    const float* v  = (const float*)d_in[1];
    const float* sr = (const float*)d_in[2];
    const float* si = (const float*)d_in[3];
    const float* er = (const float*)d_in[4];
    const float* ei = (const float*)d_in[5];
    const float* wr = (const float*)d_in[6];
    const float* wi = (const float*)d_in[7];
    const float* lw = (const float*)d_in[8];
    const float* lb = (const float*)d_in[9];
    float* out = (float*)d_out;

    float2* wenv = (float2*)d_ws;
    float2* up   = (float2*)((char*)d_ws + 4096);
    const size_t base     = 4096;
    const size_t per_copy = (size_t)NB * NT * sizeof(float2);  // 409600 B

    int pc;
    if (ws_size >= base + 8 * per_copy) {
        pc = 8;   // 256 gemm blocks, 40 MB L2 traffic — preferred
        gemm_kernel<8, 8><<<dim3((NB/8)*8 + 1), dim3(256), 0, stream>>>(
            x, v, sr, si, wr, wi, er, ei, wenv, up);
    } else if (ws_size >= base + 4 * per_copy) {
        pc = 4;   // 256 gemm blocks, 80 MB L2 traffic
        gemm_kernel<4, 4><<<dim3((NB/4)*4 + 1), dim3(256), 0, stream>>>(
            x, v, sr, si, wr, wi, er, ei, wenv, up);
    } else {
        pc = 1;   // minimal workspace fallback (slower, correct)
        gemm_kernel<4, 1><<<dim3((NB/4) + 1), dim3(256), 0, stream>>>(
            x, v, sr, si, wr, wi, er, ei, wenv, up);
    }
    epilogue_kernel<<<dim3(NB), dim3(256), 0, stream>>>(up, pc, wenv, lw, lb, out);
}

// Round 2
// 91.525 us; speedup vs baseline: 1.0638x; 1.0638x over previous
//
#include <hip/hip_runtime.h>
#include <math.h>

#define NB 256      // batch
#define NP 784      // pixels
#define NT 200      // time samples

static constexpr float TWO_PI = 6.28318530717958647692f;

// ---------------------------------------------------------------------------
// K1: partial complex GEMM  u[b,t] = sum_p x[b,p]*v[p]*(sr+i*si)[p,t]
// Block g < GB: row-group rg = g/PC (R rows), p-chunk c = g%PC (NP/PC pixels).
// Writes partial sums up[c][b][t] (float2). Extra block g == GB computes
// Wenv[t] = DFT(waveform)[t] * env[t] into ws (needed only by K2).
// R=8, PC=16 -> 512 gemm blocks (2 blocks/CU, 8 waves/CU) with the same
// 40 MB aggregate L2 traffic as R=8,PC=8 — better latency hiding.
// ---------------------------------------------------------------------------
template <int R, int PC>
__global__ __launch_bounds__(256) void gemm_kernel(
        const float* __restrict__ x,  const float* __restrict__ v,
        const float* __restrict__ sr, const float* __restrict__ si,
        const float* __restrict__ wr, const float* __restrict__ wi,
        const float* __restrict__ er, const float* __restrict__ ei,
        float2* __restrict__ wenv, float2* __restrict__ up)
{
    constexpr int CH = NP / PC;          // pixels per block
    constexpr int GB = (NB / R) * PC;    // gemm blocks
    __shared__ __align__(16) float xvT[CH][R];
    __shared__ float2 ctbl[NT];

    const int tid = threadIdx.x;
    const int g   = blockIdx.x;

    if (g == GB) {
        // ---- Wenv block: 200-point DFT of waveform, times envelope ----
        // Exact-periodic twiddles via (k*n mod 200) table — no large-arg
        // sincos reduction error. Runs once, overlapped with GEMM blocks.
        if (tid < NT) {
            float s, c;
            sincosf(TWO_PI * (float)tid / (float)NT, &s, &c);
            ctbl[tid] = make_float2(c, s);
        }
        __syncthreads();
        if (tid < NT) {
            const int k = tid;
            float Ar = 0.f, Ai = 0.f;
            int m = 0;                     // m = (k*n) mod NT, exact
            for (int n = 0; n < NT; ++n) {
                float2 cs = ctbl[m];       // e^{-i th} = c - i s
                float wrv = wr[n], wiv = wi[n];
                Ar += wrv * cs.x + wiv * cs.y;
                Ai += wiv * cs.x - wrv * cs.y;
                m += k; if (m >= NT) m -= NT;
            }
            float erv = er[k], eiv = ei[k];
            wenv[k] = make_float2(Ar * erv - Ai * eiv, Ar * eiv + Ai * erv);
        }
        return;
    }

    const int rg = g / PC, c = g % PC;
    const int r0 = rg * R;
    const int p0 = c * CH;

    // stage xv[r][p] = x[r0+r][p0+p] * v[p0+p], transposed for float4 broadcast
    for (int p = tid; p < CH; p += 256) {
        float vv = v[p0 + p];
        #pragma unroll
        for (int r = 0; r < R; ++r)
            xvT[p][r] = x[(size_t)(r0 + r) * NP + p0 + p] * vv;
    }
    __syncthreads();

    const int t = tid;
    if (t < NT) {
        float ar[R], ai[R];
        #pragma unroll
        for (int r = 0; r < R; ++r) { ar[r] = 0.f; ai[r] = 0.f; }
        const float* srp = sr + (size_t)p0 * NT + t;   // coalesced over lanes
        const float* sip = si + (size_t)p0 * NT + t;
        #pragma unroll 4                               // batch loads in flight
        for (int j = 0; j < CH; ++j) {
            float srv = srp[(size_t)j * NT];
            float siv = sip[(size_t)j * NT];
            #pragma unroll
            for (int rr = 0; rr < R; rr += 4) {
                float4 xv = *(const float4*)&xvT[j][rr];   // LDS broadcast
                ar[rr+0] += xv.x * srv;  ai[rr+0] += xv.x * siv;
                ar[rr+1] += xv.y * srv;  ai[rr+1] += xv.y * siv;
                ar[rr+2] += xv.z * srv;  ai[rr+2] += xv.z * siv;
                ar[rr+3] += xv.w * srv;  ai[rr+3] += xv.w * siv;
            }
        }
        #pragma unroll
        for (int r = 0; r < R; ++r)
            up[((size_t)c * NB + r0 + r) * NT + t] = make_float2(ar[r], ai[r]);
    }
}

// ---------------------------------------------------------------------------
// K2: per batch-row: sum partials -> *Wenv -> Re(IFFT) via rotation-twiddle
//     DFT (no LDS gather) -> chunk max(sqrt(x^2+eps)) -> 10x10 linear -> out.
// Templated on PC so the partial-sum loop fully unrolls (all loads in flight).
// Rotation twiddles: cs_{t+1} = cs_t * e^{i 2pi n/200}; fp32 drift over 200
// steps ~2e-5 relative — far under the 6e-3 output threshold.
// ---------------------------------------------------------------------------
template <int PC>
__global__ __launch_bounds__(256) void epilogue_kernel(
        const float2* __restrict__ up,
        const float2* __restrict__ wenv,
        const float* __restrict__ lw, const float* __restrict__ lb,
        float* __restrict__ out)
{
    __shared__ __align__(16) float2 s2[NT];
    __shared__ float  rbuf[NT];
    __shared__ float  cm[10];

    const int b   = blockIdx.x;
    const int tid = threadIdx.x;

    if (tid < NT) {
        float ur = 0.f, ui = 0.f;
        #pragma unroll
        for (int cc = 0; cc < PC; ++cc) {
            float2 pv = up[((size_t)cc * NB + b) * NT + tid];
            ur += pv.x; ui += pv.y;
        }
        float2 W = wenv[tid];
        s2[tid] = make_float2(ur * W.x - ui * W.y, ur * W.y + ui * W.x);
    }
    __syncthreads();

    if (tid < NT) {
        float rs, rc;
        sincosf(TWO_PI * (float)tid / (float)NT, &rs, &rc);
        float cr = 1.f, ci = 0.f, acc = 0.f;
        const float4* sv4 = (const float4*)s2;         // 2 samples per b128
        #pragma unroll 5
        for (int h = 0; h < NT / 2; ++h) {
            float4 two = sv4[h];                       // s2[2h], s2[2h+1]
            acc += two.x * cr - two.y * ci;
            float nr = cr * rc - ci * rs;              // advance twiddle
            float ni = cr * rs + ci * rc;
            acc += two.z * nr - two.w * ni;
            cr = nr * rc - ni * rs;
            ci = nr * rs + ni * rc;
        }
        rbuf[tid] = acc * (1.0f / (float)NT);
    }
    __syncthreads();

    if (tid < 10) {
        float mx = 0.f;
        #pragma unroll
        for (int q = 0; q < 20; ++q) {
            float xv = rbuf[tid * 20 + q];
            mx = fmaxf(mx, sqrtf(xv * xv + 1e-20f));
        }
        cm[tid] = mx;
    }
    __syncthreads();

    if (tid < 10) {
        float o = lb[tid];
        #pragma unroll
        for (int k = 0; k < 10; ++k)
            o += cm[k] * lw[tid * 10 + k];
        out[b * 10 + tid] = o;
    }
}

// ---------------------------------------------------------------------------
extern "C" void kernel_launch(void* const* d_in, const int* in_sizes, int n_in,
                              void* d_out, int out_size, void* d_ws, size_t ws_size,
                              hipStream_t stream)
{
    const float* x  = (const float*)d_in[0];
    const float* v  = (const float*)d_in[1];
    const float* sr = (const float*)d_in[2];
    const float* si = (const float*)d_in[3];
    const float* er = (const float*)d_in[4];
    const float* ei = (const float*)d_in[5];
    const float* wr = (const float*)d_in[6];
    const float* wi = (const float*)d_in[7];
    const float* lw = (const float*)d_in[8];
    const float* lb = (const float*)d_in[9];
    float* out = (float*)d_out;

    float2* wenv = (float2*)d_ws;
    float2* up   = (float2*)((char*)d_ws + 4096);
    const size_t base     = 4096;
    const size_t per_copy = (size_t)NB * NT * sizeof(float2);  // 409600 B

    if (ws_size >= base + 16 * per_copy) {
        // 512 gemm blocks (2/CU), 40 MB L2 traffic — preferred
        gemm_kernel<8, 16><<<dim3((NB/8)*16 + 1), dim3(256), 0, stream>>>(
            x, v, sr, si, wr, wi, er, ei, wenv, up);
        epilogue_kernel<16><<<dim3(NB), dim3(256), 0, stream>>>(up, wenv, lw, lb, out);
    } else if (ws_size >= base + 8 * per_copy) {
        gemm_kernel<8, 8><<<dim3((NB/8)*8 + 1), dim3(256), 0, stream>>>(
            x, v, sr, si, wr, wi, er, ei, wenv, up);
        epilogue_kernel<8><<<dim3(NB), dim3(256), 0, stream>>>(up, wenv, lw, lb, out);
    } else if (ws_size >= base + 4 * per_copy) {
        gemm_kernel<4, 4><<<dim3((NB/4)*4 + 1), dim3(256), 0, stream>>>(
            x, v, sr, si, wr, wi, er, ei, wenv, up);
        epilogue_kernel<4><<<dim3(NB), dim3(256), 0, stream>>>(up, wenv, lw, lb, out);
    } else {
        // minimal workspace fallback (slower, correct)
        gemm_kernel<4, 1><<<dim3((NB/4) + 1), dim3(256), 0, stream>>>(
            x, v, sr, si, wr, wi, er, ei, wenv, up);
        epilogue_kernel<1><<<dim3(NB), dim3(256), 0, stream>>>(up, wenv, lw, lb, out);
    }
}